// Round 6
// baseline (297.373 us; speedup 1.0000x reference)
//
#include <hip/hip_runtime.h>

typedef __attribute__((ext_vector_type(8))) short bf16x8;
typedef __attribute__((ext_vector_type(4))) float f32x4;

#define HH 768
#define EE 768
#define BB 32
#define SS 512
#define PP 76
#define KCAND 64
#define MM (BB * PP)     // 2432
#define VV 50257

// ws byte offsets (16B aligned)
#define OFF_WT    0u          // bf16 768*768   = 1,179,648
#define OFF_AG    1179648u    // bf16 2432*768  = 3,735,552
#define OFF_LM    4915200u    // fp32 2432*768  = 7,471,104
#define OFF_EMB   12386304u   // bf16 50257*768 = 77,194,752

#define WT_BLOCKS 576
#define AG_BLOCKS 304
#define GEMM_BLOCKS 456      // 12 x 38
#define CONV_BLOCKS 18847    // ceil(50257*768 / 2048)

__device__ inline unsigned short f2bf(float f) {
    unsigned int u = __float_as_uint(f);
    u += 0x7fffu + ((u >> 16) & 1u);
    return (unsigned short)(u >> 16);
}
__device__ inline float bf2f(unsigned short h) {
    return __uint_as_float(((unsigned int)h) << 16);
}

// L1: W transpose+convert -> Wt[e][h] ; gather masked rows -> Ag[m][k].
__global__ __launch_bounds__(256) void prep_kernel(
    const float* __restrict__ W, unsigned short* __restrict__ Wt,
    const float* __restrict__ seq, const int* __restrict__ mpos,
    unsigned short* __restrict__ Ag) {
    const int bid = blockIdx.x;
    if (bid < WT_BLOCKS) {
        __shared__ float tile[32][33];
        const int h0 = (bid % 24) * 32, e0 = (bid / 24) * 32;
        const int c = threadIdx.x & 31, r = threadIdx.x >> 5;
#pragma unroll
        for (int rr = r; rr < 32; rr += 8)
            tile[rr][c] = W[(size_t)(h0 + rr) * EE + e0 + c];
        __syncthreads();
#pragma unroll
        for (int rr = r; rr < 32; rr += 8)
            Wt[(size_t)(e0 + rr) * HH + h0 + c] = f2bf(tile[c][rr]);
    } else {
        const int m0 = (bid - WT_BLOCKS) * 8;
        const int t = threadIdx.x;
#pragma unroll
        for (int rr = 0; rr < 8; ++rr) {
            const int m = m0 + rr;
            const int b = m / PP, p = m - b * PP;
            const int ps = mpos[b * PP + p];
            const float* srow = seq + (size_t)(b * SS + ps) * HH;
            unsigned short* drow = Ag + (size_t)m * HH;
#pragma unroll
            for (int j = 0; j < 3; ++j)
                drow[t + j * 256] = f2bf(srow[t + j * 256]);
        }
    }
}

// L2: bf16 MFMA GEMM (64x64 tile, BK=64) -> lm fp32.
//     PLUS concurrent blocks: emb fp32 -> bf16 streaming conversion (154 MB
//     read at streaming efficiency instead of letting mrow fetch it as random
//     3KB bursts at ~42% DRAM efficiency). GEMM uses only 456 blocks; the
//     conversion rides on the otherwise-idle machine.
__global__ __launch_bounds__(256) void gemm_conv_kernel(
    const unsigned short* __restrict__ Ag, const unsigned short* __restrict__ Wt,
    float* __restrict__ lm, const float* __restrict__ embf,
    unsigned short* __restrict__ embB) {
    const int bid = blockIdx.x;
    if (bid >= GEMM_BLOCKS) {
        // ---- emb fp32 -> bf16, 8 elems/thread, fully coalesced ----
        const size_t i = ((size_t)(bid - GEMM_BLOCKS) * 2048) + (size_t)threadIdx.x * 8;
        if (i < (size_t)VV * EE) {
            const float4 a = *(const float4*)(embf + i);
            const float4 b = *(const float4*)(embf + i + 4);
            unsigned short o[8];
            o[0] = f2bf(a.x); o[1] = f2bf(a.y); o[2] = f2bf(a.z); o[3] = f2bf(a.w);
            o[4] = f2bf(b.x); o[5] = f2bf(b.y); o[6] = f2bf(b.z); o[7] = f2bf(b.w);
            *(int4*)(embB + i) = *(const int4*)o;
        }
        return;
    }
    __shared__ __align__(16) unsigned short Alds[64][72];
    __shared__ __align__(16) unsigned short Blds[64][72];
    const int bn = bid % 12, bm = bid / 12;
    const int tid = threadIdx.x;
    const int sr = tid >> 2, sc = (tid & 3) * 16;
    const unsigned short* abase = Ag + (size_t)(bm * 64) * HH;
    const unsigned short* bbase = Wt + (size_t)(bn * 64) * HH;
    const int lane = tid & 63, wv = tid >> 6;
    const int wm = wv >> 1, wn = wv & 1;
    const int fr = lane & 15, fq = (lane >> 4) * 8;
    f32x4 acc[2][2] = {};
    for (int kk = 0; kk < HH; kk += 64) {
        __syncthreads();
        *(int4*)&Alds[sr][sc]     = *(const int4*)(abase + (size_t)sr * HH + kk + sc);
        *(int4*)&Alds[sr][sc + 8] = *(const int4*)(abase + (size_t)sr * HH + kk + sc + 8);
        *(int4*)&Blds[sr][sc]     = *(const int4*)(bbase + (size_t)sr * HH + kk + sc);
        *(int4*)&Blds[sr][sc + 8] = *(const int4*)(bbase + (size_t)sr * HH + kk + sc + 8);
        __syncthreads();
#pragma unroll
        for (int ks = 0; ks < 64; ks += 32) {
            bf16x8 af[2], bfr[2];
#pragma unroll
            for (int t = 0; t < 2; ++t)
                af[t] = *(const bf16x8*)&Alds[wm * 32 + t * 16 + fr][ks + fq];
#pragma unroll
            for (int t = 0; t < 2; ++t)
                bfr[t] = *(const bf16x8*)&Blds[wn * 32 + t * 16 + fr][ks + fq];
#pragma unroll
            for (int tm = 0; tm < 2; ++tm)
#pragma unroll
                for (int tn = 0; tn < 2; ++tn)
                    acc[tm][tn] = __builtin_amdgcn_mfma_f32_16x16x32_bf16(
                        af[tm], bfr[tn], acc[tm][tn], 0, 0, 0);
        }
    }
#pragma unroll
    for (int tm = 0; tm < 2; ++tm)
#pragma unroll
        for (int tn = 0; tn < 2; ++tn) {
            const int col = bn * 64 + wn * 32 + tn * 16 + (lane & 15);
            const int rbase = bm * 64 + wm * 32 + tm * 16 + (lane >> 4) * 4;
#pragma unroll
            for (int g = 0; g < 4; ++g)
                lm[(size_t)(rbase + g) * EE + col] = acc[tm][tn][g];
        }
}

// L3: one block per output row m.
//  Phase A: cand -> LDS; bias + LayerNorm of lm[m] -> bf16 in LDS.
//  Phase B: 16 groups x 16 lanes; each group does its 4 candidates with all
//           24 bf16x8 emb loads issued up front. emb is the 77 MB bf16 copy,
//           freshly written -> largely L3-resident -> HBM random penalty gone.
__global__ __launch_bounds__(256) void mrow_logits_kernel(
    const float* __restrict__ lm, const float* __restrict__ bias,
    const float* __restrict__ gamma, const float* __restrict__ beta,
    const int* __restrict__ cand, const unsigned short* __restrict__ embB,
    float* __restrict__ out) {
    const int m = blockIdx.x;
    const int t = threadIdx.x;
    __shared__ __align__(16) unsigned short lmn_s[EE];
    __shared__ float redS[4], redQ[4];
    __shared__ int cand_s[KCAND];

    if (t < KCAND) cand_s[t] = cand[m * KCAND + t];

    // ---- Phase A: LayerNorm(lm[m] + bias) ----
    const float x0 = lm[(size_t)m * EE + t]       + bias[t];
    const float x1 = lm[(size_t)m * EE + t + 256] + bias[t + 256];
    const float x2 = lm[(size_t)m * EE + t + 512] + bias[t + 512];
    float s = x0 + x1 + x2;
    float q = x0 * x0 + x1 * x1 + x2 * x2;
#pragma unroll
    for (int w = 32; w; w >>= 1) { s += __shfl_xor(s, w); q += __shfl_xor(q, w); }
    const int lane = t & 63, wv = t >> 6;
    if (lane == 0) { redS[wv] = s; redQ[wv] = q; }
    __syncthreads();
    s = redS[0] + redS[1] + redS[2] + redS[3];
    q = redQ[0] + redQ[1] + redQ[2] + redQ[3];
    const float mu = s * (1.0f / 768.0f);
    const float rstd = rsqrtf(q * (1.0f / 768.0f) - mu * mu + 1e-12f);
    lmn_s[t]       = f2bf((x0 - mu) * rstd * gamma[t]       + beta[t]);
    lmn_s[t + 256] = f2bf((x1 - mu) * rstd * gamma[t + 256] + beta[t + 256]);
    lmn_s[t + 512] = f2bf((x2 - mu) * rstd * gamma[t + 512] + beta[t + 512]);
    __syncthreads();

    // ---- Phase B: 64 candidate dots, 4-wide per 16-lane group, bf16 emb ----
    const int g = t >> 4, l16 = t & 15;
    // lane's slice: elements 8*l16 + 128*j + 0..7, j = 0..5
    bf16x8 ln8[6];
#pragma unroll
    for (int j = 0; j < 6; ++j)
        ln8[j] = *(const bf16x8*)&lmn_s[8 * l16 + 128 * j];

    const bf16x8* e8 = (const bf16x8*)embB;   // row = 96 chunks of 8 bf16
    const int cb = m * KCAND + g;
    const bf16x8* p0 = e8 + (size_t)cand_s[g]      * 96 + l16;
    const bf16x8* p1 = e8 + (size_t)cand_s[g + 16] * 96 + l16;
    const bf16x8* p2 = e8 + (size_t)cand_s[g + 32] * 96 + l16;
    const bf16x8* p3 = e8 + (size_t)cand_s[g + 48] * 96 + l16;
    bf16x8 A0[6], A1[6], A2[6], A3[6];
#pragma unroll
    for (int j = 0; j < 6; ++j) A0[j] = p0[16 * j];
#pragma unroll
    for (int j = 0; j < 6; ++j) A1[j] = p1[16 * j];
#pragma unroll
    for (int j = 0; j < 6; ++j) A2[j] = p2[16 * j];
#pragma unroll
    for (int j = 0; j < 6; ++j) A3[j] = p3[16 * j];
    __builtin_amdgcn_sched_barrier(0);   // all 24 loads issued before any FMA

    float d0 = 0.f, d1 = 0.f, d2 = 0.f, d3 = 0.f;
    float f0 = 0.f, f1 = 0.f, f2 = 0.f, f3 = 0.f;
#pragma unroll
    for (int j = 0; j < 6; ++j) {
        float lv[8];
#pragma unroll
        for (int e = 0; e < 8; ++e) lv[e] = bf2f((unsigned short)ln8[j][e]);
#pragma unroll
        for (int e = 0; e < 4; ++e) {
            d0 += lv[e] * bf2f((unsigned short)A0[j][e]);
            d1 += lv[e] * bf2f((unsigned short)A1[j][e]);
            d2 += lv[e] * bf2f((unsigned short)A2[j][e]);
            d3 += lv[e] * bf2f((unsigned short)A3[j][e]);
        }
#pragma unroll
        for (int e = 4; e < 8; ++e) {
            f0 += lv[e] * bf2f((unsigned short)A0[j][e]);
            f1 += lv[e] * bf2f((unsigned short)A1[j][e]);
            f2 += lv[e] * bf2f((unsigned short)A2[j][e]);
            f3 += lv[e] * bf2f((unsigned short)A3[j][e]);
        }
    }
    d0 += f0; d1 += f1; d2 += f2; d3 += f3;
#pragma unroll
    for (int w = 1; w < 16; w <<= 1) {
        d0 += __shfl_xor(d0, w); d1 += __shfl_xor(d1, w);
        d2 += __shfl_xor(d2, w); d3 += __shfl_xor(d3, w);
    }
    if (l16 == 0) {
        out[cb]      = d0;
        out[cb + 16] = d1;
        out[cb + 32] = d2;
        out[cb + 48] = d3;
    }
}

extern "C" void kernel_launch(void* const* d_in, const int* in_sizes, int n_in,
                              void* d_out, int out_size, void* d_ws, size_t ws_size,
                              hipStream_t stream) {
    const float* seq   = (const float*)d_in[0];
    const int*   mpos  = (const int*)d_in[1];
    const int*   cand  = (const int*)d_in[2];
    const float* emb   = (const float*)d_in[3];
    const float* W     = (const float*)d_in[4];
    const float* bias  = (const float*)d_in[5];
    const float* gamma = (const float*)d_in[6];
    const float* beta  = (const float*)d_in[7];
    float* out = (float*)d_out;

    char* ws = (char*)d_ws;
    unsigned short* Wt   = (unsigned short*)(ws + OFF_WT);
    unsigned short* Ag   = (unsigned short*)(ws + OFF_AG);
    float*          lm   = (float*)(ws + OFF_LM);
    unsigned short* embB = (unsigned short*)(ws + OFF_EMB);

    prep_kernel<<<WT_BLOCKS + AG_BLOCKS, 256, 0, stream>>>(W, Wt, seq, mpos, Ag);
    gemm_conv_kernel<<<GEMM_BLOCKS + CONV_BLOCKS, 256, 0, stream>>>(
        Ag, Wt, lm, emb, embB);
    mrow_logits_kernel<<<MM, 256, 0, stream>>>(lm, bias, gamma, beta, cand, embB, out);
}